// Round 1
// baseline (920.612 us; speedup 1.0000x reference)
//
#include <hip/hip_runtime.h>

#define KSL 8
#define DIN 128
#define DOUT 128

// ---------------- CSR build ----------------

__global__ void count_deg(const int* __restrict__ dst, int E, int* __restrict__ deg) {
    int e = blockIdx.x * blockDim.x + threadIdx.x;
    if (e < E) atomicAdd(&deg[dst[e]], 1);
}

// single-block exclusive scan of deg -> off, plus dinv = rsqrt(deg+1)
__global__ void scan_off(const int* __restrict__ deg, int N,
                         int* __restrict__ off, float* __restrict__ dinv) {
    __shared__ int buf[1024];
    int tid = threadIdx.x;
    int base = 0;
    for (int c0 = 0; c0 < N; c0 += 1024) {
        int i = c0 + tid;
        int v = (i < N) ? deg[i] : 0;
        if (i < N) dinv[i] = rsqrtf((float)(v + 1));  // +1 self-loop
        buf[tid] = v;
        __syncthreads();
        for (int s = 1; s < 1024; s <<= 1) {
            int t = (tid >= s) ? buf[tid - s] : 0;
            __syncthreads();
            buf[tid] += t;
            __syncthreads();
        }
        if (i < N) off[i] = base + buf[tid] - v;   // exclusive prefix
        base += buf[1023];
        __syncthreads();
    }
    if (tid == 0) off[N] = base;
}

__global__ void fill_csr(const int* __restrict__ src, const int* __restrict__ dst, int E,
                         const int* __restrict__ off, int* __restrict__ cursor,
                         const float* __restrict__ dinv,
                         int* __restrict__ csr_src, float* __restrict__ csr_norm) {
    int e = blockIdx.x * blockDim.x + threadIdx.x;
    if (e < E) {
        int s = src[e], d = dst[e];
        int pos = atomicAdd(&cursor[d], 1);
        int idx = off[d] + pos;
        csr_src[idx] = s;
        csr_norm[idx] = dinv[s] * dinv[d];
    }
}

// ---------------- aggregation: one wave per node, all K slices ----------------
// out[node][k][d] = dinv[node]^2 * x[node][k][d] + sum_e norm_e * x[src_e][k][d]
// K*DIN = 1024 floats per node = 4 float4 per lane (64 lanes).

__global__ __launch_bounds__(256) void aggregate(
        const float* __restrict__ x, const int* __restrict__ off,
        const int* __restrict__ csr_src, const float* __restrict__ csr_norm,
        const float* __restrict__ dinv, int N, float* __restrict__ out) {
    int wid  = threadIdx.x >> 6;
    int lane = threadIdx.x & 63;
    int node = blockIdx.x * 4 + wid;
    if (node >= N) return;

    const float4* xr = (const float4*)(x + (size_t)node * (KSL * DIN));
    float di = dinv[node];
    float nrm0 = di * di;

    float4 acc[4];
    #pragma unroll
    for (int c = 0; c < 4; c++) {
        float4 v = xr[c * 64 + lane];
        acc[c].x = v.x * nrm0; acc[c].y = v.y * nrm0;
        acc[c].z = v.z * nrm0; acc[c].w = v.w * nrm0;
    }

    int e0 = off[node], e1 = off[node + 1];
    for (int e = e0; e < e1; e++) {
        int s = csr_src[e];
        float nrm = csr_norm[e];
        const float4* xs = (const float4*)(x + (size_t)s * (KSL * DIN));
        #pragma unroll
        for (int c = 0; c < 4; c++) {
            float4 v = xs[c * 64 + lane];
            acc[c].x += v.x * nrm; acc[c].y += v.y * nrm;
            acc[c].z += v.z * nrm; acc[c].w += v.w * nrm;
        }
    }

    float4* o = (float4*)(out + (size_t)node * (KSL * DIN));
    #pragma unroll
    for (int c = 0; c < 4; c++) o[c * 64 + lane] = acc[c];
}

// ---------------- in-place GEMM + bias + ReLU ----------------
// io: [rows x 128] row-major (rows = N*K). io <- relu(io @ W + b).
// Block: 256 threads, 32-row tile. Each thread computes a 4x4 micro-tile.

__global__ __launch_bounds__(256) void gemm_bias_relu(
        float* __restrict__ io, const float* __restrict__ W,
        const float* __restrict__ b, int rows) {
    __shared__ float As[128][36];   // [d][r], padded for alignment/banks
    __shared__ float Ws[32][132];   // [dd][c], one 32-d chunk of W

    int t  = threadIdx.x;
    int tx = t & 31;        // col group: cols tx*4 .. tx*4+3
    int ty = t >> 5;        // row group: rows ty*4 .. ty*4+3
    int row0 = blockIdx.x * 32;

    // stage A tile (32 rows x 128 d), transposed into LDS
    #pragma unroll
    for (int i = 0; i < 4; i++) {
        int f = i * 1024 + t * 4;           // flat index in 32x128 tile
        int r = f >> 7, d = f & 127;
        float4 v;
        if (row0 + r < rows) v = *(const float4*)(io + (size_t)(row0 + r) * 128 + d);
        else                 v = make_float4(0.f, 0.f, 0.f, 0.f);
        As[d][r] = v.x; As[d + 1][r] = v.y; As[d + 2][r] = v.z; As[d + 3][r] = v.w;
    }

    float acc[4][4];
    #pragma unroll
    for (int j = 0; j < 4; j++)
        #pragma unroll
        for (int c = 0; c < 4; c++) acc[j][c] = 0.f;

    for (int ch = 0; ch < 4; ch++) {
        __syncthreads();    // A staged / previous Ws consumed
        #pragma unroll
        for (int i = 0; i < 4; i++) {
            int f = i * 1024 + t * 4;       // flat index in 32x128 W chunk
            int dd = f >> 7, c = f & 127;
            *(float4*)&Ws[dd][c] = *(const float4*)(W + ch * 4096 + f);
        }
        __syncthreads();
        #pragma unroll
        for (int dd = 0; dd < 32; dd++) {
            int d = ch * 32 + dd;
            float4 a = *(const float4*)&As[d][ty * 4];
            float4 w = *(const float4*)&Ws[dd][tx * 4];
            acc[0][0] += a.x * w.x; acc[0][1] += a.x * w.y; acc[0][2] += a.x * w.z; acc[0][3] += a.x * w.w;
            acc[1][0] += a.y * w.x; acc[1][1] += a.y * w.y; acc[1][2] += a.y * w.z; acc[1][3] += a.y * w.w;
            acc[2][0] += a.z * w.x; acc[2][1] += a.z * w.y; acc[2][2] += a.z * w.z; acc[2][3] += a.z * w.w;
            acc[3][0] += a.w * w.x; acc[3][1] += a.w * w.y; acc[3][2] += a.w * w.z; acc[3][3] += a.w * w.w;
        }
    }

    float4 bv = *(const float4*)(b + tx * 4);
    #pragma unroll
    for (int j = 0; j < 4; j++) {
        int row = row0 + ty * 4 + j;
        if (row < rows) {
            float4 o;
            o.x = fmaxf(acc[j][0] + bv.x, 0.f);
            o.y = fmaxf(acc[j][1] + bv.y, 0.f);
            o.z = fmaxf(acc[j][2] + bv.z, 0.f);
            o.w = fmaxf(acc[j][3] + bv.w, 0.f);
            *(float4*)(io + (size_t)row * 128 + tx * 4) = o;
        }
    }
}

// ---------------- launch ----------------

extern "C" void kernel_launch(void* const* d_in, const int* in_sizes, int n_in,
                              void* d_out, int out_size, void* d_ws, size_t ws_size,
                              hipStream_t stream) {
    const float* x = (const float*)d_in[0];
    const int*   ei = (const int*)d_in[1];
    const float* W = (const float*)d_in[2];
    const float* b = (const float*)d_in[3];
    float* out = (float*)d_out;

    int N = in_sizes[0] / (KSL * DIN);
    int E = in_sizes[1] / 2;
    const int* src = ei;
    const int* dst = ei + E;

    char* ws = (char*)d_ws;
    size_t o = 0;
    auto alloc = [&](size_t bytes) -> void* {
        o = (o + 255) & ~(size_t)255;
        void* p = ws + o;
        o += bytes;
        return p;
    };
    int*   deg      = (int*)alloc((size_t)N * 4);
    int*   off      = (int*)alloc((size_t)(N + 1) * 4);
    int*   cursor   = (int*)alloc((size_t)N * 4);
    int*   csr_src  = (int*)alloc((size_t)E * 4);
    float* csr_norm = (float*)alloc((size_t)E * 4);
    float* dinv     = (float*)alloc((size_t)N * 4);

    hipMemsetAsync(deg, 0, (size_t)N * 4, stream);
    hipMemsetAsync(cursor, 0, (size_t)N * 4, stream);

    count_deg<<<(E + 255) / 256, 256, 0, stream>>>(dst, E, deg);
    scan_off<<<1, 1024, 0, stream>>>(deg, N, off, dinv);
    fill_csr<<<(E + 255) / 256, 256, 0, stream>>>(src, dst, E, off, cursor, dinv,
                                                  csr_src, csr_norm);
    aggregate<<<(N + 3) / 4, 256, 0, stream>>>(x, off, csr_src, csr_norm, dinv, N, out);

    int rows = N * KSL;
    gemm_bias_relu<<<(rows + 31) / 32, 256, 0, stream>>>(out, W, b, rows);
}

// Round 2
// 567.030 us; speedup vs baseline: 1.6236x; 1.6236x over previous
//
#include <hip/hip_runtime.h>

#define KSL 8
#define DIN 128
#define DOUT 128

typedef __attribute__((ext_vector_type(8))) short bf16x8;
typedef __attribute__((ext_vector_type(4))) float f32x4;

// round-to-nearest-even fp32 -> bf16 bits
static __device__ __forceinline__ unsigned int f2b_bits(float f) {
    unsigned int u = __float_as_uint(f);
    return (u + 0x7fffu + ((u >> 16) & 1u)) >> 16;
}

// ---------------- x fp32 -> bf16 ----------------
__global__ __launch_bounds__(256) void convert_bf16(const float* __restrict__ x,
                                                    uint4* __restrict__ xh, int n8) {
    int stride = gridDim.x * blockDim.x;
    for (int i = blockIdx.x * blockDim.x + threadIdx.x; i < n8; i += stride) {
        const float4* p = (const float4*)x + (size_t)i * 2;
        float4 a = p[0], b = p[1];
        uint4 o;
        o.x = f2b_bits(a.x) | (f2b_bits(a.y) << 16);
        o.y = f2b_bits(a.z) | (f2b_bits(a.w) << 16);
        o.z = f2b_bits(b.x) | (f2b_bits(b.y) << 16);
        o.w = f2b_bits(b.z) | (f2b_bits(b.w) << 16);
        xh[i] = o;
    }
}

// ---------------- CSR build ----------------
__global__ void count_deg(const int* __restrict__ dst, int E, int* __restrict__ deg) {
    int e = blockIdx.x * blockDim.x + threadIdx.x;
    if (e < E) atomicAdd(&deg[dst[e]], 1);
}

// serial-per-thread chunks + one 1024-wide block scan
__global__ __launch_bounds__(1024) void scan_off_fast(const int* __restrict__ deg, int N,
                                                      int* __restrict__ off,
                                                      float* __restrict__ dinv) {
    __shared__ int part[1024];
    int tid = threadIdx.x;
    int CH = (N + 1023) / 1024;
    int i0 = tid * CH;
    int s = 0;
    for (int j = 0; j < CH; j++) {
        int i = i0 + j;
        if (i < N) {
            int d = deg[i];
            dinv[i] = rsqrtf((float)(d + 1));   // +1 self-loop
            s += d;
        }
    }
    part[tid] = s;
    __syncthreads();
    for (int st = 1; st < 1024; st <<= 1) {
        int t = (tid >= st) ? part[tid - st] : 0;
        __syncthreads();
        part[tid] += t;
        __syncthreads();
    }
    int run = part[tid] - s;   // exclusive prefix
    for (int j = 0; j < CH; j++) {
        int i = i0 + j;
        if (i < N) {
            off[i] = run;
            run += deg[i];
        }
    }
    if (tid == 1023) off[N] = part[1023];
}

__global__ void fill_csr(const int* __restrict__ src, const int* __restrict__ dst, int E,
                         const int* __restrict__ off, int* __restrict__ cursor,
                         const float* __restrict__ dinv,
                         int* __restrict__ csr_src, float* __restrict__ csr_norm) {
    int e = blockIdx.x * blockDim.x + threadIdx.x;
    if (e < E) {
        int s = src[e], d = dst[e];
        int pos = atomicAdd(&cursor[d], 1);
        int idx = off[d] + pos;
        csr_src[idx] = s;
        csr_norm[idx] = dinv[s] * dinv[d];
    }
}

// ---------------- fused aggregate + MFMA GEMM + bias + ReLU ----------------
// One wave per node-pair (16 rows of the [N*K, 128] matrix). Gather layout ==
// MFMA A-frag layout: lane l owns row (l&15) -> (node, kslice), elements
// d = kt*32 + (l>>4)*8 + e. W staged transposed bf16 in LDS, XOR-swizzled.
template <int BF16>
__global__ __launch_bounds__(256) void aggemm(
        const void* __restrict__ xsrc,
        const int* __restrict__ off,
        const int* __restrict__ csr_src, const float* __restrict__ csr_norm,
        const float* __restrict__ dinv,
        const float* __restrict__ W, const float* __restrict__ bias,
        int N, float* __restrict__ out) {
    __shared__ unsigned short Wt[128 * 128];   // [c][k] bf16, swizzled, 32 KB

    int t = threadIdx.x;
    // ---- stage W^T as bf16 with XOR swizzle on byte bits 4..6 ----
    {
        int c = t & 127;
        int khalf = t >> 7;
        #pragma unroll
        for (int kc = 0; kc < 8; kc++) {
            int k0 = khalf * 64 + kc * 8;
            unsigned int u0 = f2b_bits(W[(size_t)(k0 + 0) * 128 + c]) |
                             (f2b_bits(W[(size_t)(k0 + 1) * 128 + c]) << 16);
            unsigned int u1 = f2b_bits(W[(size_t)(k0 + 2) * 128 + c]) |
                             (f2b_bits(W[(size_t)(k0 + 3) * 128 + c]) << 16);
            unsigned int u2 = f2b_bits(W[(size_t)(k0 + 4) * 128 + c]) |
                             (f2b_bits(W[(size_t)(k0 + 5) * 128 + c]) << 16);
            unsigned int u3 = f2b_bits(W[(size_t)(k0 + 6) * 128 + c]) |
                             (f2b_bits(W[(size_t)(k0 + 7) * 128 + c]) << 16);
            int byte = c * 256 + k0 * 2;
            byte ^= (c & 7) << 4;
            *(uint4*)((char*)Wt + byte) = make_uint4(u0, u1, u2, u3);
        }
    }
    __syncthreads();

    int wid = t >> 6, lane = t & 63;
    int pair = blockIdx.x * 4 + wid;
    int n0 = pair * 2;
    if (n0 >= N) return;

    int rit = lane & 15;          // row in 16-row tile
    int g   = lane >> 4;          // k-group 0..3
    int mynode = n0 + (rit >> 3);
    if (mynode >= N) mynode = n0; // odd-N guard
    int kslice = rit & 7;

    int offA = off[n0];
    int offMid = off[n0 + 1];
    int offEnd = (n0 + 2 <= N) ? off[n0 + 2] : offMid;
    int degA = offMid - offA;
    int degB = (n0 + 1 < N) ? (offEnd - offMid) : 0;
    int maxd = max(degA, degB);
    int myoff = (rit < 8) ? offA : offMid;
    int mydeg = (rit < 8) ? degA : degB;

    float acc[32];
    #pragma unroll
    for (int i = 0; i < 32; i++) acc[i] = 0.f;

    float dself = dinv[mynode];
    // iterations: j = -1 is the self-loop term, then edges
    for (int j = -1; j < maxd; j++) {
        int s;
        float nrm;
        if (j < 0) {
            s = mynode;
            nrm = dself * dself;
        } else if (j < mydeg) {
            int e = myoff + j;
            s = csr_src[e];
            nrm = csr_norm[e];
        } else {
            s = mynode;
            nrm = 0.f;
        }
        if (BF16) {
            const char* rb = (const char*)xsrc + (size_t)s * 2048 + kslice * 256 + g * 16;
            #pragma unroll
            for (int kt = 0; kt < 4; kt++) {
                uint4 q = *(const uint4*)(rb + kt * 64);
                unsigned int w0 = q.x, w1 = q.y, w2 = q.z, w3 = q.w;
                acc[kt * 8 + 0] += __uint_as_float(w0 << 16) * nrm;
                acc[kt * 8 + 1] += __uint_as_float(w0 & 0xffff0000u) * nrm;
                acc[kt * 8 + 2] += __uint_as_float(w1 << 16) * nrm;
                acc[kt * 8 + 3] += __uint_as_float(w1 & 0xffff0000u) * nrm;
                acc[kt * 8 + 4] += __uint_as_float(w2 << 16) * nrm;
                acc[kt * 8 + 5] += __uint_as_float(w2 & 0xffff0000u) * nrm;
                acc[kt * 8 + 6] += __uint_as_float(w3 << 16) * nrm;
                acc[kt * 8 + 7] += __uint_as_float(w3 & 0xffff0000u) * nrm;
            }
        } else {
            const char* rb = (const char*)xsrc + (size_t)s * 4096 + kslice * 512 + g * 32;
            #pragma unroll
            for (int kt = 0; kt < 4; kt++) {
                float4 q0 = *(const float4*)(rb + kt * 128);
                float4 q1 = *(const float4*)(rb + kt * 128 + 16);
                acc[kt * 8 + 0] += q0.x * nrm;
                acc[kt * 8 + 1] += q0.y * nrm;
                acc[kt * 8 + 2] += q0.z * nrm;
                acc[kt * 8 + 3] += q0.w * nrm;
                acc[kt * 8 + 4] += q1.x * nrm;
                acc[kt * 8 + 5] += q1.y * nrm;
                acc[kt * 8 + 6] += q1.z * nrm;
                acc[kt * 8 + 7] += q1.w * nrm;
            }
        }
    }

    // pack accumulators -> A fragments (bf16)
    bf16x8 afrag[4];
    #pragma unroll
    for (int kt = 0; kt < 4; kt++) {
        #pragma unroll
        for (int e = 0; e < 8; e++)
            afrag[kt][e] = (short)f2b_bits(acc[kt * 8 + e]);
    }

    // GEMM: 8 column tiles of 16, K = 128 in 4 MFMAs each
    long long r0 = (long long)n0 * 8;
    #pragma unroll
    for (int ct = 0; ct < 8; ct++) {
        int c = ct * 16 + rit;     // output column (C/D: col = lane&15)
        f32x4 acct = {0.f, 0.f, 0.f, 0.f};
        #pragma unroll
        for (int kt = 0; kt < 4; kt++) {
            int byte = c * 256 + kt * 64 + g * 16;
            byte ^= (c & 7) << 4;
            bf16x8 bfrag = *(const bf16x8*)((const char*)Wt + byte);
            acct = __builtin_amdgcn_mfma_f32_16x16x32_bf16(afrag[kt], bfrag, acct, 0, 0, 0);
        }
        float bv = bias[c];
        #pragma unroll
        for (int r = 0; r < 4; r++) {
            long long row = r0 + g * 4 + r;   // C/D: row = (lane>>4)*4 + reg
            out[row * 128 + c] = fmaxf(acct[r] + bv, 0.f);
        }
    }
}

// ---------------- launch ----------------
extern "C" void kernel_launch(void* const* d_in, const int* in_sizes, int n_in,
                              void* d_out, int out_size, void* d_ws, size_t ws_size,
                              hipStream_t stream) {
    const float* x  = (const float*)d_in[0];
    const int*   ei = (const int*)d_in[1];
    const float* W  = (const float*)d_in[2];
    const float* b  = (const float*)d_in[3];
    float* out = (float*)d_out;

    int N = in_sizes[0] / (KSL * DIN);
    int E = in_sizes[1] / 2;
    const int* src = ei;
    const int* dst = ei + E;

    char* ws = (char*)d_ws;
    size_t o = 0;
    auto alloc = [&](size_t bytes) -> void* {
        o = (o + 255) & ~(size_t)255;
        void* p = ws + o;
        o += bytes;
        return p;
    };
    int*   deg      = (int*)alloc((size_t)N * 4);
    int*   off      = (int*)alloc((size_t)(N + 1) * 4);
    int*   cursor   = (int*)alloc((size_t)N * 4);
    float* dinv     = (float*)alloc((size_t)N * 4);
    int*   csr_src  = (int*)alloc((size_t)E * 4);
    float* csr_norm = (float*)alloc((size_t)E * 4);

    size_t xh_bytes = (size_t)N * KSL * DIN * 2;
    size_t o_before = o;
    uint4* xh = (uint4*)alloc(xh_bytes);
    bool use_bf16 = (o <= ws_size);
    if (!use_bf16) o = o_before;

    hipMemsetAsync(deg, 0, (size_t)N * 4, stream);
    hipMemsetAsync(cursor, 0, (size_t)N * 4, stream);

    if (use_bf16) {
        int n8 = N * KSL * DIN / 8;
        convert_bf16<<<2048, 256, 0, stream>>>(x, xh, n8);
    }
    count_deg<<<(E + 255) / 256, 256, 0, stream>>>(dst, E, deg);
    scan_off_fast<<<1, 1024, 0, stream>>>(deg, N, off, dinv);
    fill_csr<<<(E + 255) / 256, 256, 0, stream>>>(src, dst, E, off, cursor, dinv,
                                                  csr_src, csr_norm);

    int pairs = (N + 1) / 2;
    int blocks = (pairs + 3) / 4;
    if (use_bf16) {
        aggemm<1><<<blocks, 256, 0, stream>>>(xh, off, csr_src, csr_norm, dinv,
                                              W, b, N, out);
    } else {
        aggemm<0><<<blocks, 256, 0, stream>>>(x, off, csr_src, csr_norm, dinv,
                                              W, b, N, out);
    }
}